// Round 2
// baseline (532.117 us; speedup 1.0000x reference)
//
#include <hip/hip_runtime.h>

// MaxPool2d 2x2 stride 1 VALID, NCHW fp32.
// In:  (16, 96, 224, 224)  Out: (16, 96, 223, 223)
//
// Round-2 structure:
//  - Persistent grid-stride loop, 2048 blocks (G11: memory-bound ops want a
//    small resident grid, not 9408 one-shot blocks).
//  - Fully uniform, branch-free body: the last column group OVERLAPS (w=219,
//    recomputing output col 219 with identical values) and the last row strip
//    overlaps (h0=215, recomputing output row 215). No tail paths, no wave
//    divergence, no scalar edge stores. Benign same-value double writes.
//  - All 9 input rows of the strip loaded upfront -> 18 vmem in flight/wave.
//  - Nontemporal stores: output is write-once, never re-read; nt bit avoids
//    cache-allocate churn against the input read stream.
//
// Loads: dwordx4 (16B-aligned except the one overlap lane, 4B-aligned -> HW ok)
// Stores: dwordx4 (4B-aligned, odd 223-row width).

#define W_IN    224
#define HW_IN   (224 * 224)
#define W_OUT   223
#define HW_OUT  (223 * 223)
#define CGROUPS 56   // col groups of 4 outputs; last group overlaps at w=219
#define RSTRIPS 28   // row strips of 8 output rows; last strip overlaps at h0=215
#define JOBS    (16 * 96 * RSTRIPS * CGROUPS)   // 2,408,448
#define NBLOCKS 2048

typedef float f4u __attribute__((ext_vector_type(4), aligned(4)));  // dword-aligned vec4

__global__ __launch_bounds__(256, 6) void maxpool2x2_s1_strip8u(
    const float* __restrict__ in, float* __restrict__ out) {
  const int stride = NBLOCKS * 256;
  for (int job = blockIdx.x * 256 + threadIdx.x; job < JOBS; job += stride) {
    int cg = job % CGROUPS;             // fast-varying -> coalesced columns
    int t  = job / CGROUPS;
    int rs = t % RSTRIPS;
    int nc = t / RSTRIPS;               // n*96 + c

    int w  = cg * 4;  if (w > 219) w = 219;    // overlap last col group
    int h0 = rs * 8;  if (h0 > 215) h0 = 215;  // overlap last row strip

    const float* p = in  + (size_t)nc * HW_IN  + (size_t)h0 * W_IN  + w;
    float*       q = out + (size_t)nc * HW_OUT + (size_t)h0 * W_OUT + w;

    // Load the whole 9-row x 5-col input strip first (max MLP).
    f4u   row[9];
    float e[9];
    #pragma unroll
    for (int r = 0; r < 9; ++r) {
      const float* pr = p + r * W_IN;
      row[r] = *(const f4u*)pr;   // dwordx4
      e[r]   = pr[4];             // col w+4 (cg=55: col 223, in bounds)
    }

    // 8 output rows, register-resident vertical reuse.
    #pragma unroll
    for (int r = 0; r < 8; ++r) {
      f4u a = row[r], b = row[r + 1];
      float vx = fmaxf(a.x, b.x);
      float vy = fmaxf(a.y, b.y);
      float vz = fmaxf(a.z, b.z);
      float vw = fmaxf(a.w, b.w);
      float v4 = fmaxf(e[r], e[r + 1]);

      f4u o;
      o.x = fmaxf(vx, vy);
      o.y = fmaxf(vy, vz);
      o.z = fmaxf(vz, vw);
      o.w = fmaxf(vw, v4);
      __builtin_nontemporal_store(o, (f4u*)(q + (size_t)r * W_OUT));
    }
  }
}

extern "C" void kernel_launch(void* const* d_in, const int* in_sizes, int n_in,
                              void* d_out, int out_size, void* d_ws, size_t ws_size,
                              hipStream_t stream) {
  const float* x = (const float*)d_in[0];
  float* out = (float*)d_out;
  int blocks = NBLOCKS;
  int maxb = (JOBS + 255) / 256;
  if (blocks > maxb) blocks = maxb;
  maxpool2x2_s1_strip8u<<<blocks, 256, 0, stream>>>(x, out);
}